// Round 13
// baseline (497.814 us; speedup 1.0000x reference)
//
#include <hip/hip_runtime.h>
#include <hip/hip_bf16.h>
#include <stdint.h>

// Graph_Refine: N=8192, D=128, E=262144, P=4, eps=0.3. fp32 I/O.
// R13: gemm's pinned ~150us attributed to 1.06 GB of panel reads served by L3
// (per-XCD L2 = 4MiB < yb 8MB; x-major dispatch spreads panels across XCDs).
// Fix: XCD-banded 1D grid — xcd=o&7 owns bm in {xcd+8j}, bn-major traversal ->
// concurrent window ~3MB/XCD fits L2; L3 traffic 1.06GB -> ~72MB. Full grid
// (no upper-tri/transpose), nt stores keep write stream out of L2.
// Keeps R12's validated: glds+swizzle K-loop, fused fix/edges, folded memset,
// FIX_DELTA 0.0043. Harness floor ~250us poison fills.
#define N_NODES 8192
#define DIM     128
#define KTOT    512
#define NEDGE   262144
#define EPS     0.3f
#define FIX_DELTA 0.0043f  // > provable bf16 dot bound 2^-8*Sum|ab| <= 0.0039
#define FIX_CAP (1u << 19)
#define XCAP    (1u << 18)
#define LCAP    512
#define HASH_BITS 19
#define HASH_SLOTS (1u << HASH_BITS)

typedef unsigned int u32;
typedef unsigned short u16;
typedef __attribute__((ext_vector_type(8))) short short8;
typedef __attribute__((ext_vector_type(4))) float float4v;

// workspace layout (bytes)
#define OFF_YF  0u           // fp32 Y [8192][512] 16 MB
#define OFF_YB  16777216u    // bf16 Y  8 MB
#define OFF_CTR 25165824u    // counters: fc@0, uc@4, xc@8
#define OFF_HK  25166080u    // hash keys u32[2^19] 2 MB
#define OFF_HV  27263232u    // hash vals f32[2^19] 2 MB
#define OFF_FL  29360384u    // fixup list u32 2 MB
#define OFF_UL  31457536u    // unique list u32 1 MB
#define OFF_XL  32506112u    // exact-fallback list u32 1 MB
#define ZERO_VEC4 262160u    // (OFF_FL-OFF_CTR)/16 uint4s zeroed in prep_y

__device__ __forceinline__ u16 f2bf(float f) {  // RNE
    u32 b = __builtin_bit_cast(u32, f);
    b += 0x7fffu + ((b >> 16) & 1u);
    return (u16)(b >> 16);
}

// K1: reweight + L2-normalize per perspective; Y fp32 + bf16 (0.5 folds mean over P).
// Blocks >= 2048 zero the counter+hash region (replaces hipMemsetAsync).
__global__ void prep_y(const float* __restrict__ x, const float* __restrict__ wp,
                       float* __restrict__ yf, u16* __restrict__ yb,
                       uint4* __restrict__ zbase) {
    if (blockIdx.x >= 2048) {
        for (u32 idx = (blockIdx.x - 2048) * 256 + threadIdx.x; idx < ZERO_VEC4;
             idx += 512 * 256)
            zbase[idx] = make_uint4(0, 0, 0, 0);
        return;
    }
    int node = blockIdx.x * 4 + (threadIdx.x >> 6);
    int lane = threadIdx.x & 63;
    float x0 = x[node * DIM + lane];
    float x1 = x[node * DIM + lane + 64];
    for (int p = 0; p < 4; ++p) {
        float v0 = x0 * wp[p * DIM + lane];
        float v1 = x1 * wp[p * DIM + lane + 64];
        float ss = v0 * v0 + v1 * v1;
        #pragma unroll
        for (int o = 1; o < 64; o <<= 1) ss += __shfl_xor(ss, o, 64);
        float scale = 0.5f / fmaxf(sqrtf(ss), 1e-12f);
        float y0 = v0 * scale, y1 = v1 * scale;
        int base = node * KTOT + p * DIM;
        yf[base + lane] = y0;       yf[base + lane + 64] = y1;
        yb[base + lane] = f2bf(y0); yb[base + lane + 64] = f2bf(y1);
    }
}

// K2: hash-aggregate duplicate edges + compact unique-slot list
__global__ void edge_insert(const int* __restrict__ idx, const float* __restrict__ w,
                            u32* __restrict__ hkey, float* __restrict__ hval,
                            u32* __restrict__ ucnt, u32* __restrict__ ulist) {
    int e = blockIdx.x * 256 + threadIdx.x;
    u32 cell = (u32)(idx[e] * N_NODES + idx[NEDGE + e]);
    float wv = w[e];
    u32 key = cell + 1u;
    u32 h = (cell * 2654435761u) >> (32 - HASH_BITS);
    while (true) {
        u32 old = atomicCAS(&hkey[h], 0u, key);
        if (old == 0u) { ulist[atomicAdd(ucnt, 1u)] = h; atomicAdd(&hval[h], wv); break; }
        if (old == key) { atomicAdd(&hval[h], wv); break; }
        h = (h + 1u) & (HASH_SLOTS - 1u);
    }
}

// K3: sim = Yb*Yb^T. 128x128 tile, 512 thr / 8 waves (4x2), 32x64 per wave.
// 1D grid, XCD-banded: o&7 = xcd owns bm in {xcd+8j}; bn-major within band.
#define TM  128
#define BK  64

__global__ __launch_bounds__(512)
void gemm_sim(const u16* __restrict__ yb, float* __restrict__ out,
              u32* __restrict__ fcnt, u32* __restrict__ flst) {
    int o = blockIdx.x;
    int g = o >> 3;
    int bn = g >> 3;                           // bn-major: B-panel shared across band
    int bm = (o & 7) + 8 * (g & 7);            // XCD (o&7) owns 8 bm-panels
    __shared__ __align__(16) u16 As[TM * BK];  // 16 KB
    __shared__ __align__(16) u16 Bs[TM * BK];  // 16 KB
    __shared__ u32 s_cnt, s_base;
    __shared__ u32 s_list[LCAP];
    int tid = threadIdx.x;
    int lane = tid & 63, wid = tid >> 6;       // 8 waves
    int wm = wid >> 1, wn = wid & 1;           // 4x2: rows [wm*32,+32) x cols [wn*64,+64)
    if (tid == 0) s_cnt = 0;

    float4v acc[2][4] = {};
    const u16* arow = yb + (size_t)(bm * TM) * KTOT;
    const u16* brow = yb + (size_t)(bn * TM) * KTOT;

    for (int kt = 0; kt < KTOT / BK; ++kt) {
        __syncthreads();
        #pragma unroll
        for (int q = 0; q < 2; ++q) {
            int c = q * 512 + wid * 64 + lane;  // chunk id 0..1023 (16B units)
            int row = c >> 3;
            int kg = (c & 7) ^ (row & 7);       // source-side XOR swizzle
            __builtin_amdgcn_global_load_lds(
                (const __attribute__((address_space(1))) void*)(const void*)(arow + (size_t)row * KTOT + kt * BK + kg * 8),
                (__attribute__((address_space(3))) void*)(void*)(As + (q * 512 + wid * 64) * 8),
                16, 0, 0);
            __builtin_amdgcn_global_load_lds(
                (const __attribute__((address_space(1))) void*)(const void*)(brow + (size_t)row * KTOT + kt * BK + kg * 8),
                (__attribute__((address_space(3))) void*)(void*)(Bs + (q * 512 + wid * 64) * 8),
                16, 0, 0);
        }
        __syncthreads();
        #pragma unroll
        for (int kk = 0; kk < 2; ++kk) {
            short8 af[2], bfr[4];
            int kg2 = kk * 4 + (lane >> 4);
            int mrow = wm * 32 + (lane & 15);
            int ncol = wn * 64 + (lane & 15);
            #pragma unroll
            for (int i = 0; i < 2; ++i) {
                int ra = mrow + i * 16;
                af[i] = *(const short8*)&As[ra * BK + ((kg2 ^ (ra & 7)) * 8)];
            }
            #pragma unroll
            for (int j = 0; j < 4; ++j) {
                int rb = ncol + j * 16;
                bfr[j] = *(const short8*)&Bs[rb * BK + ((kg2 ^ (rb & 7)) * 8)];
            }
            #pragma unroll
            for (int i = 0; i < 2; ++i)
                #pragma unroll
                for (int j = 0; j < 4; ++j)
                    acc[i][j] = __builtin_amdgcn_mfma_f32_16x16x32_bf16(
                        af[i], bfr[j], acc[i][j], 0, 0, 0);
        }
    }

    // epilogue: dense thresholded nt stores + knife-edge flags (per-cell; the
    // mirror block computes a bitwise-identical dot and flags its own side).
    // C/D: col=lane&15, row=(lane>>4)*4+reg [m89/m91]
    int quad = lane >> 4, lcol = lane & 15;
    #pragma unroll
    for (int i = 0; i < 2; ++i)
        #pragma unroll
        for (int j = 0; j < 4; ++j) {
            int gr0 = bm * TM + wm * 32 + i * 16 + quad * 4;
            int gc  = bn * TM + wn * 64 + j * 16 + lcol;
            #pragma unroll
            for (int r = 0; r < 4; ++r) {
                float s = acc[i][j][r];
                __builtin_nontemporal_store(s > EPS ? s : 0.f,
                                            &out[(size_t)(gr0 + r) * N_NODES + gc]);
                if (fabsf(s - EPS) < FIX_DELTA) {
                    u32 cell = (u32)((gr0 + r) * N_NODES + gc);
                    u32 li = atomicAdd(&s_cnt, 1u);
                    if (li < LCAP) s_list[li] = cell;
                    else { u32 g2 = atomicAdd(fcnt, 1u); if (g2 < FIX_CAP) flst[g2] = cell; }
                }
            }
        }
    __syncthreads();
    u32 cnt = s_cnt < LCAP ? s_cnt : LCAP;
    if (tid == 0) s_base = atomicAdd(fcnt, cnt);
    __syncthreads();
    for (u32 t = tid; t < cnt; t += 512) {
        u32 g2 = s_base + t;
        if (g2 < FIX_CAP) flst[g2] = s_list[t];
    }
}

// exact fp32 dot of rows i,j of Y (16-lane team)
__device__ __forceinline__ float dot_exact(const float* __restrict__ yf,
                                           u32 i, u32 j, int tl) {
    const float4v* ri = (const float4v*)(yf + (size_t)i * KTOT);
    const float4v* rj = (const float4v*)(yf + (size_t)j * KTOT);
    float4v p = {};
    #pragma unroll
    for (int q = 0; q < 8; ++q) p += ri[q * 16 + tl] * rj[q * 16 + tl];
    float s = p.x + p.y + p.z + p.w;
    #pragma unroll
    for (int o = 8; o >= 1; o >>= 1) s += __shfl_xor(s, o, 16);
    return s;
}

// K4 (fused): blocks [0,1024) = fixup (exact recompute, single orientation — both
// sides are flagged independently); blocks [1024,1536) = edge_fast (sim-reuse;
// punts a>1 / knife-edge / (sg==0,a>0.97) to exact list; edge_exact runs last).
__global__ void fix_and_edges(const float* __restrict__ yf,
                              const u32* __restrict__ fcnt, const u32* __restrict__ flst,
                              const u32* __restrict__ hkey, const float* __restrict__ hval,
                              const u32* __restrict__ ucnt, const u32* __restrict__ ulist,
                              float* __restrict__ out,
                              u32* __restrict__ xcnt, u32* __restrict__ xlist) {
    if (blockIdx.x < 1024) {                    // ---- fixup part
        u32 count = *fcnt; if (count > FIX_CAP) count = FIX_CAP;
        int team = (blockIdx.x * 256 + threadIdx.x) >> 4;
        int tl = threadIdx.x & 15;
        int nteams = 1024 * 16;
        for (u32 t = team; t < count; t += nteams) {
            u32 cell = flst[t];
            u32 i = cell >> 13, j = cell & 8191u;
            float s = dot_exact(yf, i, j, tl);
            if (tl == 0) out[cell] = s > EPS ? s : 0.f;
        }
    } else {                                    // ---- edge_fast part
        u32 count = *ucnt;
        for (u32 t = (blockIdx.x - 1024) * 256 + threadIdx.x; t < count; t += 512 * 256) {
            u32 h = ulist[t];
            u32 cell = hkey[h] - 1u;
            float a = hval[h];
            float sg = out[cell];
            bool hard = (a > 1.0f) ||
                        (fabsf(sg - EPS) < FIX_DELTA + 1e-6f) ||
                        (sg > 0.f && fabsf(sg * a - EPS) < FIX_DELTA * a + 1e-6f) ||
                        (sg == 0.f && a > 0.97f);
            if (hard) {
                u32 g = atomicAdd(xcnt, 1u);
                if (g < XCAP) xlist[g] = h;
            } else if (sg > 0.f) {
                out[cell] = sg + ((sg * a > EPS) ? a : 0.f);
            }
        }
    }
}

// K5: exact final value for hard edge cells (runs last, wins all races)
__global__ void edge_exact(const float* __restrict__ yf, const u32* __restrict__ hkey,
                           const float* __restrict__ hval, const u32* __restrict__ xcnt,
                           const u32* __restrict__ xlist, float* __restrict__ out) {
    u32 count = *xcnt; if (count > XCAP) count = XCAP;
    int team = (blockIdx.x * 256 + threadIdx.x) >> 4;
    int tl = threadIdx.x & 15;
    int nteams = gridDim.x * 16;
    for (u32 t = team; t < count; t += nteams) {
        u32 h = xlist[t];
        u32 cell = hkey[h] - 1u;
        float a = hval[h];
        u32 i = cell >> 13, j = cell & 8191u;
        float s = dot_exact(yf, i, j, tl);
        if (tl == 0) {
            float v = s > EPS ? s : 0.f;
            if (s * a > EPS) v += a;
            out[cell] = v;
        }
    }
}

extern "C" void kernel_launch(void* const* d_in, const int* in_sizes, int n_in,
                              void* d_out, int out_size, void* d_ws, size_t ws_size,
                              hipStream_t stream) {
    const float* x  = (const float*)d_in[0];
    const int*   oi = (const int*)d_in[1];
    const float* ow = (const float*)d_in[2];
    const float* wp = (const float*)d_in[3];
    float* out = (float*)d_out;
    char* ws = (char*)d_ws;
    float* yf = (float*)(ws + OFF_YF);
    u16*   yb = (u16*)(ws + OFF_YB);
    u32*   fc = (u32*)(ws + OFF_CTR);
    u32*   uc = (u32*)(ws + OFF_CTR + 4);
    u32*   xc = (u32*)(ws + OFF_CTR + 8);
    u32*   hk = (u32*)(ws + OFF_HK);
    float* hv = (float*)(ws + OFF_HV);
    u32*   fl = (u32*)(ws + OFF_FL);
    u32*   ul = (u32*)(ws + OFF_UL);
    u32*   xl = (u32*)(ws + OFF_XL);

    prep_y<<<2560, 256, 0, stream>>>(x, wp, yf, yb, (uint4*)(ws + OFF_CTR));
    edge_insert<<<NEDGE / 256, 256, 0, stream>>>(oi, ow, hk, hv, uc, ul);
    gemm_sim<<<4096, 512, 0, stream>>>(yb, out, fc, fl);
    fix_and_edges<<<1536, 256, 0, stream>>>(yf, fc, fl, hk, hv, uc, ul, out, xc, xl);
    edge_exact<<<256, 256, 0, stream>>>(yf, hk, hv, xc, xl, out);
}

// Round 14
// 467.658 us; speedup vs baseline: 1.0645x; 1.0645x over previous
//
#include <hip/hip_runtime.h>
#include <hip/hip_bf16.h>
#include <stdint.h>

// Graph_Refine: N=8192, D=128, E=262144, P=4, eps=0.3. fp32 I/O.
// R14 = R12 verbatim (measured best: 469.6us). Final configuration.
// Ledger: ~238us harness poison fills (untouchable) + ~150us gemm (pinned across
// 10 structural variants: staging x3, occupancy x2, tiles x3, barrier-free,
// store policy x3, XCD scheduling — all pipes <10% busy; latency floor of the
// K=512 gram on this memory system) + ~45us exact-math tail + ~35us gaps.
// Real wins on the path here: atomic de-storm (R3, 2.5x), kill RMW epilogue
// (R5), sim-reuse for edges (R6), upper-tri+LDS-transpose (R7), 512-thr (R9),
// fused tail + folded memset + nt stores (R11/R12).
#define N_NODES 8192
#define DIM     128
#define KTOT    512
#define NEDGE   262144
#define EPS     0.3f
#define FIX_DELTA 0.0043f  // > provable bf16 dot bound 2^-8*Sum|ab| <= 0.0039
#define FIX_CAP (1u << 19)
#define XCAP    (1u << 18)
#define LCAP    512
#define HASH_BITS 19
#define HASH_SLOTS (1u << HASH_BITS)

typedef unsigned int u32;
typedef unsigned short u16;
typedef __attribute__((ext_vector_type(8))) short short8;
typedef __attribute__((ext_vector_type(4))) float float4v;

// workspace layout (bytes)
#define OFF_YF  0u           // fp32 Y [8192][512] 16 MB
#define OFF_YB  16777216u    // bf16 Y  8 MB
#define OFF_CTR 25165824u    // counters: fc@0, uc@4, xc@8
#define OFF_HK  25166080u    // hash keys u32[2^19] 2 MB
#define OFF_HV  27263232u    // hash vals f32[2^19] 2 MB
#define OFF_FL  29360384u    // fixup list u32 2 MB
#define OFF_UL  31457536u    // unique list u32 1 MB
#define OFF_XL  32506112u    // exact-fallback list u32 1 MB
#define ZERO_VEC4 262160u    // (OFF_FL-OFF_CTR)/16 uint4s zeroed in prep_y

__device__ __forceinline__ u16 f2bf(float f) {  // RNE
    u32 b = __builtin_bit_cast(u32, f);
    b += 0x7fffu + ((b >> 16) & 1u);
    return (u16)(b >> 16);
}

// K1: reweight + L2-normalize per perspective; Y fp32 + bf16 (0.5 folds mean over P).
// Blocks >= 2048 zero the counter+hash region (replaces hipMemsetAsync).
__global__ void prep_y(const float* __restrict__ x, const float* __restrict__ wp,
                       float* __restrict__ yf, u16* __restrict__ yb,
                       uint4* __restrict__ zbase) {
    if (blockIdx.x >= 2048) {
        for (u32 idx = (blockIdx.x - 2048) * 256 + threadIdx.x; idx < ZERO_VEC4;
             idx += 512 * 256)
            zbase[idx] = make_uint4(0, 0, 0, 0);
        return;
    }
    int node = blockIdx.x * 4 + (threadIdx.x >> 6);
    int lane = threadIdx.x & 63;
    float x0 = x[node * DIM + lane];
    float x1 = x[node * DIM + lane + 64];
    for (int p = 0; p < 4; ++p) {
        float v0 = x0 * wp[p * DIM + lane];
        float v1 = x1 * wp[p * DIM + lane + 64];
        float ss = v0 * v0 + v1 * v1;
        #pragma unroll
        for (int o = 1; o < 64; o <<= 1) ss += __shfl_xor(ss, o, 64);
        float scale = 0.5f / fmaxf(sqrtf(ss), 1e-12f);
        float y0 = v0 * scale, y1 = v1 * scale;
        int base = node * KTOT + p * DIM;
        yf[base + lane] = y0;       yf[base + lane + 64] = y1;
        yb[base + lane] = f2bf(y0); yb[base + lane + 64] = f2bf(y1);
    }
}

// K2: hash-aggregate duplicate edges + compact unique-slot list
__global__ void edge_insert(const int* __restrict__ idx, const float* __restrict__ w,
                            u32* __restrict__ hkey, float* __restrict__ hval,
                            u32* __restrict__ ucnt, u32* __restrict__ ulist) {
    int e = blockIdx.x * 256 + threadIdx.x;
    u32 cell = (u32)(idx[e] * N_NODES + idx[NEDGE + e]);
    float wv = w[e];
    u32 key = cell + 1u;
    u32 h = (cell * 2654435761u) >> (32 - HASH_BITS);
    while (true) {
        u32 old = atomicCAS(&hkey[h], 0u, key);
        if (old == 0u) { ulist[atomicAdd(ucnt, 1u)] = h; atomicAdd(&hval[h], wv); break; }
        if (old == key) { atomicAdd(&hval[h], wv); break; }
        h = (h + 1u) & (HASH_SLOTS - 1u);
    }
}

// K3: sim = Yb*Yb^T, upper-tri tiles, 512 threads / 8 waves (4x2), 32x64 per wave.
#define TM  128
#define BK  64
#define TLD 132   // transpose stride (floats): conflict-free at b128, 16B aligned

__global__ __launch_bounds__(512)
void gemm_sim(const u16* __restrict__ yb, float* __restrict__ out,
              u32* __restrict__ fcnt, u32* __restrict__ flst) {
    int bm = blockIdx.y, bn = blockIdx.x;
    if (bm > bn) return;                       // symmetric: upper triangle only
    __shared__ __align__(16) char smem[64 * TLD * 4];   // 33792 B: As+Bs | tbuf
    u16* As = (u16*)smem;
    u16* Bs = As + TM * BK;
    float* tbuf = (float*)smem;                // used only after K-loop
    __shared__ u32 s_cnt, s_base;
    __shared__ u32 s_list[LCAP];
    int tid = threadIdx.x;
    int lane = tid & 63, wid = tid >> 6;       // 8 waves
    int wm = wid >> 1, wn = wid & 1;           // 4x2: rows [wm*32,+32) x cols [wn*64,+64)
    if (tid == 0) s_cnt = 0;

    float4v acc[2][4] = {};
    const u16* arow = yb + (size_t)(bm * TM) * KTOT;
    const u16* brow = yb + (size_t)(bn * TM) * KTOT;

    for (int kt = 0; kt < KTOT / BK; ++kt) {
        __syncthreads();
        #pragma unroll
        for (int q = 0; q < 2; ++q) {
            int c = q * 512 + wid * 64 + lane;  // chunk id 0..1023 (16B units)
            int row = c >> 3;
            int kg = (c & 7) ^ (row & 7);       // source-side XOR swizzle
            __builtin_amdgcn_global_load_lds(
                (const __attribute__((address_space(1))) void*)(const void*)(arow + (size_t)row * KTOT + kt * BK + kg * 8),
                (__attribute__((address_space(3))) void*)(void*)(As + (q * 512 + wid * 64) * 8),
                16, 0, 0);
            __builtin_amdgcn_global_load_lds(
                (const __attribute__((address_space(1))) void*)(const void*)(brow + (size_t)row * KTOT + kt * BK + kg * 8),
                (__attribute__((address_space(3))) void*)(void*)(Bs + (q * 512 + wid * 64) * 8),
                16, 0, 0);
        }
        __syncthreads();
        #pragma unroll
        for (int kk = 0; kk < 2; ++kk) {
            short8 af[2], bfr[4];
            int kg2 = kk * 4 + (lane >> 4);
            int mrow = wm * 32 + (lane & 15);
            int ncol = wn * 64 + (lane & 15);
            #pragma unroll
            for (int i = 0; i < 2; ++i) {
                int ra = mrow + i * 16;
                af[i] = *(const short8*)&As[ra * BK + ((kg2 ^ (ra & 7)) * 8)];
            }
            #pragma unroll
            for (int j = 0; j < 4; ++j) {
                int rb = ncol + j * 16;
                bfr[j] = *(const short8*)&Bs[rb * BK + ((kg2 ^ (rb & 7)) * 8)];
            }
            #pragma unroll
            for (int i = 0; i < 2; ++i)
                #pragma unroll
                for (int j = 0; j < 4; ++j)
                    acc[i][j] = __builtin_amdgcn_mfma_f32_16x16x32_bf16(
                        af[i], bfr[j], acc[i][j], 0, 0, 0);
        }
    }

    // epilogue A: dense thresholded direct stores (nt) + knife-edge flags (once per
    // pair; fixup writes both orientations). C/D: col=lane&15, row=quad*4+r [m89/m91]
    int quad = lane >> 4, lcol = lane & 15;
    #pragma unroll
    for (int i = 0; i < 2; ++i)
        #pragma unroll
        for (int j = 0; j < 4; ++j) {
            int gr0 = bm * TM + wm * 32 + i * 16 + quad * 4;
            int gc  = bn * TM + wn * 64 + j * 16 + lcol;
            #pragma unroll
            for (int r = 0; r < 4; ++r) {
                float s = acc[i][j][r];
                __builtin_nontemporal_store(s > EPS ? s : 0.f,
                                            &out[(size_t)(gr0 + r) * N_NODES + gc]);
                if (fabsf(s - EPS) < FIX_DELTA) {
                    u32 cell = (u32)((gr0 + r) * N_NODES + gc);
                    u32 li = atomicAdd(&s_cnt, 1u);
                    if (li < LCAP) s_list[li] = cell;
                    else { u32 g = atomicAdd(fcnt, 1u); if (g < FIX_CAP) flst[g] = cell; }
                }
            }
        }

    // epilogue B: mirrored tile via LDS transpose, two half-passes (waves wn==h write)
    #pragma unroll
    for (int h = 0; h < 2; ++h) {
        __syncthreads();
        if (wn == h) {
            #pragma unroll
            for (int i = 0; i < 2; ++i) {
                int Lr = wm * 32 + i * 16 + quad * 4;
                #pragma unroll
                for (int j = 0; j < 4; ++j) {
                    int Lc = j * 16 + lcol;
                    *(float4v*)&tbuf[Lc * TLD + Lr] = acc[i][j];
                }
            }
        }
        __syncthreads();
        #pragma unroll
        for (int v = 0; v < 4; ++v) {
            int chunk = v * 512 + tid;          // 2048 float4 = 64x128 floats
            int row = chunk >> 5, c4 = chunk & 31;
            float4v t = *(const float4v*)&tbuf[row * TLD + c4 * 4];
            float4v o;
            #pragma unroll
            for (int r = 0; r < 4; ++r) o[r] = t[r] > EPS ? t[r] : 0.f;
            __builtin_nontemporal_store(o,
                (float4v*)&out[(size_t)(bn * TM + h * 64 + row) * N_NODES + bm * TM + c4 * 4]);
        }
    }

    __syncthreads();
    u32 cnt = s_cnt < LCAP ? s_cnt : LCAP;
    if (tid == 0) s_base = atomicAdd(fcnt, cnt);
    __syncthreads();
    for (u32 t = tid; t < cnt; t += 512) {
        u32 g = s_base + t;
        if (g < FIX_CAP) flst[g] = s_list[t];
    }
}

// exact fp32 dot of rows i,j of Y (16-lane team)
__device__ __forceinline__ float dot_exact(const float* __restrict__ yf,
                                           u32 i, u32 j, int tl) {
    const float4v* ri = (const float4v*)(yf + (size_t)i * KTOT);
    const float4v* rj = (const float4v*)(yf + (size_t)j * KTOT);
    float4v p = {};
    #pragma unroll
    for (int q = 0; q < 8; ++q) p += ri[q * 16 + tl] * rj[q * 16 + tl];
    float s = p.x + p.y + p.z + p.w;
    #pragma unroll
    for (int o = 8; o >= 1; o >>= 1) s += __shfl_xor(s, o, 16);
    return s;
}

// K4 (fused): blocks [0,1024) = fixup: exact recompute of knife-edge cells, writes
// BOTH orientations (gemm flags upper only). Blocks [1024,1536) = edge_fast:
// sim-reuse; punts to exact list when a>1, |sg-eps|<delta, |sg*a-eps|<delta*a, or
// (sg==0 && a>0.97) — edge_exact runs last and fully rewrites punted cells.
__global__ void fix_and_edges(const float* __restrict__ yf,
                              const u32* __restrict__ fcnt, const u32* __restrict__ flst,
                              const u32* __restrict__ hkey, const float* __restrict__ hval,
                              const u32* __restrict__ ucnt, const u32* __restrict__ ulist,
                              float* __restrict__ out,
                              u32* __restrict__ xcnt, u32* __restrict__ xlist) {
    if (blockIdx.x < 1024) {                    // ---- fixup part
        u32 count = *fcnt; if (count > FIX_CAP) count = FIX_CAP;
        int team = (blockIdx.x * 256 + threadIdx.x) >> 4;
        int tl = threadIdx.x & 15;
        int nteams = 1024 * 16;
        for (u32 t = team; t < count; t += nteams) {
            u32 cell = flst[t];
            u32 i = cell >> 13, j = cell & 8191u;
            float s = dot_exact(yf, i, j, tl);
            if (tl == 0) {
                float v = s > EPS ? s : 0.f;
                out[(size_t)i * N_NODES + j] = v;
                out[(size_t)j * N_NODES + i] = v;
            }
        }
    } else {                                    // ---- edge_fast part
        u32 count = *ucnt;
        for (u32 t = (blockIdx.x - 1024) * 256 + threadIdx.x; t < count; t += 512 * 256) {
            u32 h = ulist[t];
            u32 cell = hkey[h] - 1u;
            float a = hval[h];
            float sg = out[cell];
            bool hard = (a > 1.0f) ||
                        (fabsf(sg - EPS) < FIX_DELTA + 1e-6f) ||
                        (sg > 0.f && fabsf(sg * a - EPS) < FIX_DELTA * a + 1e-6f) ||
                        (sg == 0.f && a > 0.97f);
            if (hard) {
                u32 g = atomicAdd(xcnt, 1u);
                if (g < XCAP) xlist[g] = h;
            } else if (sg > 0.f) {
                out[cell] = sg + ((sg * a > EPS) ? a : 0.f);
            }
        }
    }
}

// K5: exact final value for hard edge cells (runs last, wins all races)
__global__ void edge_exact(const float* __restrict__ yf, const u32* __restrict__ hkey,
                           const float* __restrict__ hval, const u32* __restrict__ xcnt,
                           const u32* __restrict__ xlist, float* __restrict__ out) {
    u32 count = *xcnt; if (count > XCAP) count = XCAP;
    int team = (blockIdx.x * 256 + threadIdx.x) >> 4;
    int tl = threadIdx.x & 15;
    int nteams = gridDim.x * 16;
    for (u32 t = team; t < count; t += nteams) {
        u32 h = xlist[t];
        u32 cell = hkey[h] - 1u;
        float a = hval[h];
        u32 i = cell >> 13, j = cell & 8191u;
        float s = dot_exact(yf, i, j, tl);
        if (tl == 0) {
            float v = s > EPS ? s : 0.f;
            if (s * a > EPS) v += a;
            out[cell] = v;
        }
    }
}

extern "C" void kernel_launch(void* const* d_in, const int* in_sizes, int n_in,
                              void* d_out, int out_size, void* d_ws, size_t ws_size,
                              hipStream_t stream) {
    const float* x  = (const float*)d_in[0];
    const int*   oi = (const int*)d_in[1];
    const float* ow = (const float*)d_in[2];
    const float* wp = (const float*)d_in[3];
    float* out = (float*)d_out;
    char* ws = (char*)d_ws;
    float* yf = (float*)(ws + OFF_YF);
    u16*   yb = (u16*)(ws + OFF_YB);
    u32*   fc = (u32*)(ws + OFF_CTR);
    u32*   uc = (u32*)(ws + OFF_CTR + 4);
    u32*   xc = (u32*)(ws + OFF_CTR + 8);
    u32*   hk = (u32*)(ws + OFF_HK);
    float* hv = (float*)(ws + OFF_HV);
    u32*   fl = (u32*)(ws + OFF_FL);
    u32*   ul = (u32*)(ws + OFF_UL);
    u32*   xl = (u32*)(ws + OFF_XL);

    prep_y<<<2560, 256, 0, stream>>>(x, wp, yf, yb, (uint4*)(ws + OFF_CTR));
    edge_insert<<<NEDGE / 256, 256, 0, stream>>>(oi, ow, hk, hv, uc, ul);
    gemm_sim<<<dim3(N_NODES / TM, N_NODES / TM), 512, 0, stream>>>(yb, out, fc, fl);
    fix_and_edges<<<1536, 256, 0, stream>>>(yf, fc, fl, hk, hv, uc, ul, out, xc, xl);
    edge_exact<<<256, 256, 0, stream>>>(yf, hk, hv, xc, xl, out);
}